// Round 7
// baseline (445.887 us; speedup 1.0000x reference)
//
#include <hip/hip_runtime.h>
#include <stdint.h>

#define BB 2048
#define TT 200
#define DD 64
#define FF 256   // 4*D
#define H1C 256
#define H2C 128
#define H3C 64

typedef __bf16 bf16x8 __attribute__((ext_vector_type(8)));
typedef float floatx16 __attribute__((ext_vector_type(16)));
typedef float f32x4 __attribute__((ext_vector_type(4)));
typedef uint32_t u32x4 __attribute__((ext_vector_type(4)));
typedef uint32_t u32x2 __attribute__((ext_vector_type(2)));
typedef unsigned short u16;
typedef u16 u16x8 __attribute__((ext_vector_type(8)));

__device__ inline u16 f2bf(float f) {
    uint32_t u = __builtin_bit_cast(uint32_t, f) + 0x8000u;
    return (u16)(u >> 16);
}
__device__ inline float bf2f(u16 h) {
    uint32_t u = ((uint32_t)h) << 16;
    return __builtin_bit_cast(float, u);
}
__device__ inline uint32_t pkbf(float lo, float hi) {
    uint32_t ul = __builtin_bit_cast(uint32_t, lo) + 0x8000u;
    uint32_t uh = __builtin_bit_cast(uint32_t, hi) + 0x8000u;
    return __builtin_amdgcn_perm(uh, ul, 0x07060302);
}
// 2-bit bank-phase swizzle: rows r, r+8, r+16, r+24 (which share bank phase at
// dword-stride ≡ 4 mod 32) get 4 distinct column-group rotations.
__device__ inline int swzf(int row) { return (row >> 3) & 3; }

// ---- pack (Wa + sgn*Wb)[K][N] fp32 -> bf16 MFMA A-fragments of W^T ----
template<int K, int N>
__device__ inline void pack_w2_dev(const float* __restrict__ Wa, const float* __restrict__ Wb,
                                   float sgn, u16* __restrict__ out, int blk) {
    constexpr int NC = K / 16;
    int idx = blk * 256 + threadIdx.x;
    int j    = idx & 7;
    int lane = (idx >> 3) & 63;
    int rest = idx >> 9;
    int c  = rest % NC;
    int mt = rest / NC;
    int k = c * 16 + ((lane >> 5) << 3) + j;
    int n = mt * 32 + (lane & 31);
    out[idx] = f2bf(Wa[k * N + n] + sgn * Wb[k * N + n]);
}
// ---- alpha pack: alpha[T][N] -> bf16, transposed-C/D epilogue order, 32-row groups ----
template<int NTOT>
__device__ inline void pack_a_dev(const float* __restrict__ A, u16* __restrict__ out, int blk) {
    constexpr int MTOT = NTOT / 32;
    int idx = blk * 256 + threadIdx.x;
    int reg  = idx & 15;
    int lane = (idx >> 4) & 63;
    int rest = idx >> 10;
    int mt = rest % MTOT;
    int g  = rest / MTOT;                 // 32-row group 0..7
    int t  = g * 32 + (lane & 31);
    int n  = mt * 32 + (reg & 3) + ((reg >> 2) << 3) + ((lane >> 5) << 2);
    out[idx] = (t < TT) ? f2bf(A[t * NTOT + n]) : (u16)0;
}

__global__ void pack_all(const float* __restrict__ W1, const float* __restrict__ W2,
                         const float* __restrict__ W3, const float* __restrict__ a1,
                         const float* __restrict__ a2, const float* __restrict__ a3,
                         u16* W1kdp, u16* W1pp, u16* W1qdp, u16* W2p, u16* W3p,
                         u16* A1p, u16* A2p, u16* A3p) {
    int blk = blockIdx.x;
    const float* W1q = W1;
    const float* W1k = W1 + 64 * H1C;
    const float* W1d = W1 + 128 * H1C;
    const float* W1p = W1 + 192 * H1C;
    if      (blk < 64)  pack_w2_dev<64, H1C>(W1k, W1d, -1.f, W1kdp, blk);
    else if (blk < 128) pack_w2_dev<64, H1C>(W1p, W1p,  0.f, W1pp,  blk - 64);
    else if (blk < 192) pack_w2_dev<64, H1C>(W1q, W1d,  1.f, W1qdp, blk - 128);
    else if (blk < 320) pack_w2_dev<H1C, H2C>(W2, W2,   0.f, W2p,   blk - 192);
    else if (blk < 352) pack_w2_dev<H2C, H3C>(W3, W3,   0.f, W3p,   blk - 320);
    else if (blk < 608) pack_a_dev<H1C>(a1, A1p, blk - 352);
    else if (blk < 736) pack_a_dev<H2C>(a2, A2p, blk - 608);
    else                pack_a_dev<H3C>(a3, A3p, blk - 736);
}

// PReLU + bf16-pack + swizzled b64 stores of one lane's 16-reg C column-quads.
__device__ __attribute__((always_inline)) inline
void store_tile(u16* yrow, int S, const floatx16& acc, u16x8 av0, u16x8 av1) {
#pragma unroll
    for (int q = 0; q < 4; ++q) {
        float p[4];
#pragma unroll
        for (int i = 0; i < 4; ++i) {
            const int r = q * 4 + i;
            float v = acc[r];
            float al = bf2f(r < 8 ? av0[r] : av1[r - 8]);
            p[i] = fmaxf(v, 0.f) + al * fminf(v, 0.f);
        }
        u32x2 pw = { pkbf(p[0], p[1]), pkbf(p[2], p[3]) };
        *reinterpret_cast<u32x2*>(yrow + ((q ^ S) << 3)) = pw;
    }
}

__device__ inline void load_k2(const float* __restrict__ Kin, int b, int t, int c0,
                               f32x4& a, f32x4& c) {
    if (t < TT) {
        const f32x4* p = reinterpret_cast<const f32x4*>(Kin + ((size_t)b * TT + t) * DD + c0);
        a = __builtin_nontemporal_load(p);
        c = __builtin_nontemporal_load(p + 1);
    } else {
        a = f32x4{0.f, 0.f, 0.f, 0.f};
        c = f32x4{0.f, 0.f, 0.f, 0.f};
    }
}

__global__ __launch_bounds__(256, 3)
void attn_pool_kernel(const float* __restrict__ Q, const float* __restrict__ Kin,
                      const u16* __restrict__ W1kdp, const u16* __restrict__ W1pp,
                      const u16* __restrict__ W1qdp, const float* __restrict__ b1,
                      const u16* __restrict__ A1p,
                      const u16* __restrict__ W2p, const float* __restrict__ b2,
                      const u16* __restrict__ A2p,
                      const u16* __restrict__ W3p, const float* __restrict__ b3,
                      const u16* __restrict__ A3p,
                      const float* __restrict__ Wl, const float* __restrict__ bl,
                      float* __restrict__ Out) {
    __shared__ __align__(16) u16 k_sh[2][32 * 72];  // bf16 k, double-buffered
    __shared__ __align__(16) u16 h1s[32 * 264];     // h1; h3 overlays cols 0..63
    __shared__ __align__(16) u16 h2s[32 * 136];
    __shared__ float q_sh[64];
    __shared__ float k0_sh[2][32];
    __shared__ float fb1_sh[H1C];                   // folded layer1 bias
    __shared__ float b2_sh[H2C];
    __shared__ float b3_sh[H3C];
    __shared__ float pool_red[4][64];

    const int tid  = threadIdx.x;
    const int lane = tid & 63;
    const int w    = tid >> 6;          // 0..3
    const int b    = blockIdx.x;
    const int tl   = lane & 31;
    const int hl   = lane >> 5;
    const int kq   = hl << 3;
    const int hsel = hl << 2;
    const int swzv = swzf(tl);          // this lane's row bank-phase
    const int r    = tid >> 3;          // staging row 0..31
    const int g    = tid & 7;           // staging col group
    const int c0   = g << 3;

    if (tid < 16) {
        reinterpret_cast<f32x4*>(q_sh)[tid] =
            reinterpret_cast<const f32x4*>(Q + (size_t)b * DD)[tid];
    }
    if (tid < H2C) b2_sh[tid] = b2[tid];
    if (tid < H3C) b3_sh[tid] = b3[tid];
    const float bl0 = bl[0];

    f32x4 kn0, kn1;
    load_k2(Kin, b, r, c0, kn0, kn1);
    __syncthreads();                    // q_sh ready

    // ---- per-batch fold: M = (W1k-W1d) + W1p*q ; fb1 = b1 + (W1q+W1d)^T q
    bf16x8 mf[2][4];                    // 32 VGPRs persistent
#pragma unroll
    for (int s = 0; s < 2; ++s) {
        const int mt = w + 4 * s;
        const size_t fo = ((size_t)(mt * 4) * 64 + lane) * 8;
        floatx16 accb;
#pragma unroll
        for (int i = 0; i < 16; ++i) accb[i] = 0.f;
#pragma unroll
        for (int c = 0; c < 4; ++c) {
            u16x8 kd = *reinterpret_cast<const u16x8*>(W1kdp + fo + (size_t)c * 512);
            u16x8 pf = *reinterpret_cast<const u16x8*>(W1pp  + fo + (size_t)c * 512);
            bf16x8 qd = *reinterpret_cast<const bf16x8*>(W1qdp + fo + (size_t)c * 512);
            f32x4 qa = *reinterpret_cast<const f32x4*>(&q_sh[c * 16 + kq]);
            f32x4 qb = *reinterpret_cast<const f32x4*>(&q_sh[c * 16 + kq + 4]);
            u32x4 qpack = { pkbf(qa[0], qa[1]), pkbf(qa[2], qa[3]),
                            pkbf(qb[0], qb[1]), pkbf(qb[2], qb[3]) };
            bf16x8 qf = __builtin_bit_cast(bf16x8, qpack);
            accb = __builtin_amdgcn_mfma_f32_32x32x16_bf16(qd, qf, accb, 0, 0, 0);
            float mv[8];
#pragma unroll
            for (int j = 0; j < 4; ++j) mv[j]     = bf2f(kd[j])     + bf2f(pf[j])     * qa[j];
#pragma unroll
            for (int j = 0; j < 4; ++j) mv[4 + j] = bf2f(kd[4 + j]) + bf2f(pf[4 + j]) * qb[j];
            u32x4 mpack = { pkbf(mv[0], mv[1]), pkbf(mv[2], mv[3]),
                            pkbf(mv[4], mv[5]), pkbf(mv[6], mv[7]) };
            mf[s][c] = __builtin_bit_cast(bf16x8, mpack);
        }
        if (tl == 0) {                  // accb replicated across tl; one writer per hl
#pragma unroll
            for (int q = 0; q < 4; ++q) {
                f32x4 bv = *reinterpret_cast<const f32x4*>(b1 + mt * 32 + q * 8 + hsel);
#pragma unroll
                for (int i = 0; i < 4; ++i)
                    fb1_sh[mt * 32 + q * 8 + hsel + i] = accb[q * 4 + i] + bv[i];
            }
        }
    }

    // ---- persistent W2 fragments (mt = w)
    bf16x8 wf2[16];                     // 64 VGPRs
    {
        const u16* p2 = W2p + (size_t)(w * 16) * 512 + lane * 8;
#pragma unroll
        for (int c = 0; c < 16; ++c)
            wf2[c] = *reinterpret_cast<const bf16x8*>(p2 + (size_t)c * 512);
    }

    float pacc = 0.f;

#pragma unroll 1
    for (int mb = 0; mb < 8; ++mb) {
        const int t0  = mb * 32;
        const int buf = mb & 1;
        u16* ksh = k_sh[buf];

        // ---- stage k (bf16) from prefetched registers (swizzled)
        {
            f32x4 kc0 = kn0, kc1 = kn1;
            if (mb < 7) load_k2(Kin, b, t0 + 32 + r, c0, kn0, kn1);
            u32x4 uk = { pkbf(kc0[0], kc0[1]), pkbf(kc0[2], kc0[3]),
                         pkbf(kc1[0], kc1[1]), pkbf(kc1[2], kc1[3]) };
            *reinterpret_cast<u32x4*>(ksh + r * 72 + ((g ^ swzf(r)) << 3)) = uk;
            if (g == 0) k0_sh[buf][r] = kc0[0];
        }
        __syncthreads();                                            // (1) k ready

        // ---- layer1: K=64 folded-M; wave w -> mt = {w, w+4}
#pragma unroll
        for (int s = 0; s < 2; ++s) {
            const int mt = w + 4 * s;
            const u16* ap = A1p + (((size_t)(mb * 8 + mt) * 64 + lane) << 4);
            u16x8 av0 = *reinterpret_cast<const u16x8*>(ap);
            u16x8 av1 = *reinterpret_cast<const u16x8*>(ap + 8);
            floatx16 acc;
#pragma unroll
            for (int q = 0; q < 4; ++q) {
                f32x4 bv = *reinterpret_cast<const f32x4*>(&fb1_sh[mt * 32 + q * 8 + hsel]);
#pragma unroll
                for (int i = 0; i < 4; ++i) acc[q * 4 + i] = bv[i];
            }
            const u16* xb = ksh + tl * 72;
#pragma unroll
            for (int c = 0; c < 4; ++c)
                acc = __builtin_amdgcn_mfma_f32_32x32x16_bf16(
                    mf[s][c],
                    *reinterpret_cast<const bf16x8*>(xb + (((2 * c + hl) ^ swzv) << 3)),
                    acc, 0, 0, 0);
            store_tile(h1s + tl * 264 + mt * 32 + hsel, swzv, acc, av0, av1);
        }
        __syncthreads();                                            // (2) h1 ready

        // ---- layer2: persistent wf2 (mt = w)
        {
            const u16* ap = A2p + (((size_t)(mb * 4 + w) * 64 + lane) << 4);
            u16x8 av0 = *reinterpret_cast<const u16x8*>(ap);
            u16x8 av1 = *reinterpret_cast<const u16x8*>(ap + 8);
            floatx16 acc;
#pragma unroll
            for (int q = 0; q < 4; ++q) {
                f32x4 bv = *reinterpret_cast<const f32x4*>(&b2_sh[w * 32 + q * 8 + hsel]);
#pragma unroll
                for (int i = 0; i < 4; ++i) acc[q * 4 + i] = bv[i];
            }
            const u16* xb = h1s + tl * 264;
#pragma unroll
            for (int c = 0; c < 16; ++c)
                acc = __builtin_amdgcn_mfma_f32_32x32x16_bf16(
                    wf2[c],
                    *reinterpret_cast<const bf16x8*>(xb + (((2 * c + hl) ^ swzv) << 3)),
                    acc, 0, 0, 0);
            store_tile(h2s + tl * 136 + w * 32 + hsel, swzv, acc, av0, av1);
        }
        __syncthreads();                                            // (3) h2 ready

        // ---- layer3: waves 0-1, mt = w; weights streamed (L2-hot)
        if (w < 2) {
            const u16* ap = A3p + (((size_t)(mb * 2 + w) * 64 + lane) << 4);
            u16x8 av0 = *reinterpret_cast<const u16x8*>(ap);
            u16x8 av1 = *reinterpret_cast<const u16x8*>(ap + 8);
            const u16* wp3 = W3p + (size_t)(w * 8) * 512 + lane * 8;
            floatx16 acc;
#pragma unroll
            for (int q = 0; q < 4; ++q) {
                f32x4 bv = *reinterpret_cast<const f32x4*>(&b3_sh[w * 32 + q * 8 + hsel]);
#pragma unroll
                for (int i = 0; i < 4; ++i) acc[q * 4 + i] = bv[i];
            }
            const u16* xb = h2s + tl * 136;
#pragma unroll
            for (int c = 0; c < 8; ++c)
                acc = __builtin_amdgcn_mfma_f32_32x32x16_bf16(
                    *reinterpret_cast<const bf16x8*>(wp3 + (size_t)c * 512),
                    *reinterpret_cast<const bf16x8*>(xb + (((2 * c + hl) ^ swzv) << 3)),
                    acc, 0, 0, 0);
            store_tile(h1s + tl * 264 + w * 32 + hsel, swzv, acc, av0, av1);
        }
        __syncthreads();                                            // (4) h3 ready

        // ---- score + pooling fused (no trailing barrier: k_sh double-buffered)
        {
            const int sr = tid >> 3;          // row 8w .. 8w+7
            const int p  = tid & 7;
            const int ss = swzf(sr);
            u16x8 hv = *reinterpret_cast<const u16x8*>(h1s + sr * 264 + ((p ^ ss) << 3));
            const f32x4 wl0 = *reinterpret_cast<const f32x4*>(Wl + p * 8);
            const f32x4 wl1 = *reinterpret_cast<const f32x4*>(Wl + p * 8 + 4);
            float s = 0.f;
#pragma unroll
            for (int i = 0; i < 4; ++i) s += bf2f(hv[i]) * wl0[i];
#pragma unroll
            for (int i = 0; i < 4; ++i) s += bf2f(hv[4 + i]) * wl1[i];
            s += __shfl_xor(s, 1);
            s += __shfl_xor(s, 2);
            s += __shfl_xor(s, 4);
            const int t = t0 + sr;
            float sc = s + bl0;
            if (t >= TT || k0_sh[buf][sr] == 0.f) sc = 0.f;
#pragma unroll
            for (int i = 0; i < 8; ++i) {
                const int row = w * 8 + i;
                float si = __shfl(sc, 8 * i);
                pacc += si * bf2f(ksh[row * 72 + (((lane >> 3) ^ swzf(row)) << 3) + (lane & 7)]);
            }
        }
        // next staging writes k_sh[buf^1] / k0_sh[buf^1]; h1s protected by (1)
    }

    pool_red[w][lane] = pacc;
    __syncthreads();
    if (tid < 64) {
        Out[(size_t)b * DD + tid] = pool_red[0][tid] + pool_red[1][tid]
                                  + pool_red[2][tid] + pool_red[3][tid];
    }
}

extern "C" void kernel_launch(void* const* d_in, const int* in_sizes, int n_in,
                              void* d_out, int out_size, void* d_ws, size_t ws_size,
                              hipStream_t stream) {
    (void)in_sizes; (void)n_in; (void)out_size; (void)ws_size;
    const float* Q  = (const float*)d_in[0];
    const float* Kk = (const float*)d_in[1];
    const float* W1 = (const float*)d_in[2];
    const float* b1 = (const float*)d_in[3];
    const float* a1 = (const float*)d_in[4];
    const float* W2 = (const float*)d_in[5];
    const float* b2 = (const float*)d_in[6];
    const float* a2 = (const float*)d_in[7];
    const float* W3 = (const float*)d_in[8];
    const float* b3 = (const float*)d_in[9];
    const float* a3 = (const float*)d_in[10];
    const float* Wl = (const float*)d_in[11];
    const float* bl = (const float*)d_in[12];
    float* Out = (float*)d_out;

    u16* ws    = (u16*)d_ws;
    u16* W1kdp = ws;                       // 16384 bf16
    u16* W1pp  = W1kdp + 16384;            // 16384
    u16* W1qdp = W1pp  + 16384;            // 16384
    u16* W2p   = W1qdp + 16384;            // 32768
    u16* W3p   = W2p   + 32768;            //  8192
    u16* A1p   = W3p   + 8192;             // 65536
    u16* A2p   = A1p   + 65536;            // 32768
    u16* A3p   = A2p   + 32768;            // 16384

    hipLaunchKernelGGL(pack_all, dim3(800), dim3(256), 0, stream,
                       W1, W2, W3, a1, a2, a3,
                       W1kdp, W1pp, W1qdp, W2p, W3p, A1p, A2p, A3p);
    hipLaunchKernelGGL(attn_pool_kernel, dim3(BB), dim3(256), 0, stream,
                       Q, Kk, W1kdp, W1pp, W1qdp, b1, A1p, W2p, b2, A2p,
                       W3p, b3, A3p, Wl, bl, Out);
}

// Round 8
// 307.191 us; speedup vs baseline: 1.4515x; 1.4515x over previous
//
#include <hip/hip_runtime.h>
#include <stdint.h>

#define BB 2048
#define TT 200
#define DD 64
#define FF 256   // 4*D
#define H1C 256
#define H2C 128
#define H3C 64

typedef __bf16 bf16x8 __attribute__((ext_vector_type(8)));
typedef float floatx16 __attribute__((ext_vector_type(16)));
typedef float f32x4 __attribute__((ext_vector_type(4)));
typedef uint32_t u32x4 __attribute__((ext_vector_type(4)));
typedef uint32_t u32x2 __attribute__((ext_vector_type(2)));
typedef unsigned short u16;
typedef u16 u16x8 __attribute__((ext_vector_type(8)));

__device__ inline u16 f2bf(float f) {
    uint32_t u = __builtin_bit_cast(uint32_t, f) + 0x8000u;
    return (u16)(u >> 16);
}
__device__ inline float bf2f(u16 h) {
    uint32_t u = ((uint32_t)h) << 16;
    return __builtin_bit_cast(float, u);
}
__device__ inline uint32_t pkbf(float lo, float hi) {
    uint32_t ul = __builtin_bit_cast(uint32_t, lo) + 0x8000u;
    uint32_t uh = __builtin_bit_cast(uint32_t, hi) + 0x8000u;
    return __builtin_amdgcn_perm(uh, ul, 0x07060302);
}

// ---- pack (Wa + sgn*Wb)[K][N] fp32 -> bf16 MFMA A-fragments of W^T ----
template<int K, int N>
__device__ inline void pack_w2_dev(const float* __restrict__ Wa, const float* __restrict__ Wb,
                                   float sgn, u16* __restrict__ out, int blk) {
    constexpr int NC = K / 16;
    int idx = blk * 256 + threadIdx.x;
    int j    = idx & 7;
    int lane = (idx >> 3) & 63;
    int rest = idx >> 9;
    int c  = rest % NC;
    int mt = rest / NC;
    int k = c * 16 + ((lane >> 5) << 3) + j;
    int n = mt * 32 + (lane & 31);
    out[idx] = f2bf(Wa[k * N + n] + sgn * Wb[k * N + n]);
}
// ---- alpha pack: alpha[T][N] -> bf16, transposed-C/D epilogue order, 32-row groups ----
template<int NTOT>
__device__ inline void pack_a_dev(const float* __restrict__ A, u16* __restrict__ out, int blk) {
    constexpr int MTOT = NTOT / 32;
    int idx = blk * 256 + threadIdx.x;
    int reg  = idx & 15;
    int lane = (idx >> 4) & 63;
    int rest = idx >> 10;
    int mt = rest % MTOT;
    int g  = rest / MTOT;                 // 32-row group 0..7
    int t  = g * 32 + (lane & 31);
    int n  = mt * 32 + (reg & 3) + ((reg >> 2) << 3) + ((lane >> 5) << 2);
    out[idx] = (t < TT) ? f2bf(A[t * NTOT + n]) : (u16)0;
}

__global__ void pack_all(const float* __restrict__ W1, const float* __restrict__ W2,
                         const float* __restrict__ W3, const float* __restrict__ a1,
                         const float* __restrict__ a2, const float* __restrict__ a3,
                         u16* W1kdp, u16* W1pp, u16* W1qdp, u16* W2p, u16* W3p,
                         u16* A1p, u16* A2p, u16* A3p) {
    int blk = blockIdx.x;
    const float* W1q = W1;
    const float* W1k = W1 + 64 * H1C;
    const float* W1d = W1 + 128 * H1C;
    const float* W1p = W1 + 192 * H1C;
    if      (blk < 64)  pack_w2_dev<64, H1C>(W1k, W1d, -1.f, W1kdp, blk);
    else if (blk < 128) pack_w2_dev<64, H1C>(W1p, W1p,  0.f, W1pp,  blk - 64);
    else if (blk < 192) pack_w2_dev<64, H1C>(W1q, W1d,  1.f, W1qdp, blk - 128);
    else if (blk < 320) pack_w2_dev<H1C, H2C>(W2, W2,   0.f, W2p,   blk - 192);
    else if (blk < 352) pack_w2_dev<H2C, H3C>(W3, W3,   0.f, W3p,   blk - 320);
    else if (blk < 608) pack_a_dev<H1C>(a1, A1p, blk - 352);
    else if (blk < 736) pack_a_dev<H2C>(a2, A2p, blk - 608);
    else                pack_a_dev<H3C>(a3, A3p, blk - 736);
}

// PReLU + bf16-pack + S-swizzled b64 stores of (accA+accB) column-quads.
__device__ __attribute__((always_inline)) inline
void store_tile(u16* yrow, int S, const floatx16& accA, const floatx16& accB,
                u16x8 av0, u16x8 av1) {
#pragma unroll
    for (int q = 0; q < 4; ++q) {
        float p[4];
#pragma unroll
        for (int i = 0; i < 4; ++i) {
            const int r = q * 4 + i;
            float v = accA[r] + accB[r];
            float al = bf2f(r < 8 ? av0[r] : av1[r - 8]);
            p[i] = fmaxf(v, 0.f) + al * fminf(v, 0.f);
        }
        u32x2 pw = { pkbf(p[0], p[1]), pkbf(p[2], p[3]) };
        *reinterpret_cast<u32x2*>(yrow + ((q ^ S) << 3)) = pw;
    }
}

__device__ inline void load_k4(const float* __restrict__ Kin, int b, int t, int c0,
                               f32x4* kk) {
    if (t < TT) {
        const f32x4* p = reinterpret_cast<const f32x4*>(Kin + ((size_t)b * TT + t) * DD + c0);
#pragma unroll
        for (int i = 0; i < 4; ++i) kk[i] = __builtin_nontemporal_load(p + i);
    } else {
#pragma unroll
        for (int i = 0; i < 4; ++i) kk[i] = f32x4{0.f, 0.f, 0.f, 0.f};
    }
}

__global__ __launch_bounds__(256, 2)
void attn_pool_kernel(const float* __restrict__ Q, const float* __restrict__ Kin,
                      const u16* __restrict__ W1kdp, const u16* __restrict__ W1pp,
                      const u16* __restrict__ W1qdp, const float* __restrict__ b1,
                      const u16* __restrict__ A1p,
                      const u16* __restrict__ W2p, const float* __restrict__ b2,
                      const u16* __restrict__ A2p,
                      const u16* __restrict__ W3p, const float* __restrict__ b3,
                      const u16* __restrict__ A3p,
                      const float* __restrict__ Wl, const float* __restrict__ bl,
                      float* __restrict__ Out) {
    __shared__ __align__(16) u16 k_sh[2][64 * 72];  // bf16 k, double-buffered, S-swizzled
    __shared__ __align__(16) u16 h1s[64 * 264];
    __shared__ __align__(16) u16 h2s[64 * 136];
    __shared__ float q_sh[64];
    __shared__ float k0_sh[2][64];
    __shared__ float fb1_sh[H1C];
    __shared__ float b2_sh[H2C];
    __shared__ float b3_sh[H3C];
    __shared__ float scorep[2][64];
    __shared__ float pool_red[4][64];

    const int tid  = threadIdx.x;
    const int lane = tid & 63;
    const int w    = tid >> 6;          // 0..3
    const int b    = blockIdx.x;
    const int tl   = lane & 31;
    const int hl   = lane >> 5;
    const int kq   = hl << 3;
    const int hsel = hl << 2;
    const int S    = (tl >> 3) & 1;     // row bank-phase bit
    const int r    = tid >> 2;          // staging row 0..63
    const int c0   = (tid & 3) << 4;    // staging col group (16 cols)
    const int Sr   = (r >> 3) & 1;

    if (tid < 16) {
        reinterpret_cast<f32x4*>(q_sh)[tid] =
            reinterpret_cast<const f32x4*>(Q + (size_t)b * DD)[tid];
    }
    if (tid < H2C) b2_sh[tid] = b2[tid];
    if (tid < H3C) b3_sh[tid] = b3[tid];
    const float bl0 = bl[0];

    f32x4 kn[4];
    load_k4(Kin, b, r, c0, kn);
    __syncthreads();                    // q_sh ready

    // ---- per-batch fold: M = (W1k-W1d) + W1p*q ; fb1 = b1 + (W1q+W1d)^T q
    bf16x8 mf[2][4];                    // 32 VGPRs persistent
#pragma unroll
    for (int s = 0; s < 2; ++s) {
        const int mt = w + 4 * s;
        const size_t fo = ((size_t)(mt * 4) * 64 + lane) * 8;
        floatx16 accb;
#pragma unroll
        for (int i = 0; i < 16; ++i) accb[i] = 0.f;
#pragma unroll
        for (int c = 0; c < 4; ++c) {
            u16x8 kd = *reinterpret_cast<const u16x8*>(W1kdp + fo + (size_t)c * 512);
            u16x8 pf = *reinterpret_cast<const u16x8*>(W1pp  + fo + (size_t)c * 512);
            bf16x8 qd = *reinterpret_cast<const bf16x8*>(W1qdp + fo + (size_t)c * 512);
            f32x4 qa = *reinterpret_cast<const f32x4*>(&q_sh[c * 16 + kq]);
            f32x4 qb = *reinterpret_cast<const f32x4*>(&q_sh[c * 16 + kq + 4]);
            u32x4 qpack = { pkbf(qa[0], qa[1]), pkbf(qa[2], qa[3]),
                            pkbf(qb[0], qb[1]), pkbf(qb[2], qb[3]) };
            bf16x8 qf = __builtin_bit_cast(bf16x8, qpack);
            accb = __builtin_amdgcn_mfma_f32_32x32x16_bf16(qd, qf, accb, 0, 0, 0);
            float mv[8];
#pragma unroll
            for (int j = 0; j < 4; ++j) mv[j]     = bf2f(kd[j])     + bf2f(pf[j])     * qa[j];
#pragma unroll
            for (int j = 0; j < 4; ++j) mv[4 + j] = bf2f(kd[4 + j]) + bf2f(pf[4 + j]) * qb[j];
            u32x4 mpack = { pkbf(mv[0], mv[1]), pkbf(mv[2], mv[3]),
                            pkbf(mv[4], mv[5]), pkbf(mv[6], mv[7]) };
            mf[s][c] = __builtin_bit_cast(bf16x8, mpack);
        }
        if (tl == 0) {
#pragma unroll
            for (int q = 0; q < 4; ++q) {
                f32x4 bv = *reinterpret_cast<const f32x4*>(b1 + mt * 32 + q * 8 + hsel);
#pragma unroll
                for (int i = 0; i < 4; ++i)
                    fb1_sh[mt * 32 + q * 8 + hsel + i] = accb[q * 4 + i] + bv[i];
            }
        }
    }

    // ---- persistent W2 (mt = w) and W3 (mt3) fragments
    const int mt3 = w & 1, tt3 = w >> 1;
    bf16x8 wf2[16], wf3[8];             // 64 + 32 VGPRs
    {
        const u16* p2 = W2p + (size_t)(w * 16) * 512 + lane * 8;
#pragma unroll
        for (int c = 0; c < 16; ++c)
            wf2[c] = *reinterpret_cast<const bf16x8*>(p2 + (size_t)c * 512);
        const u16* p3 = W3p + (size_t)(mt3 * 8) * 512 + lane * 8;
#pragma unroll
        for (int c = 0; c < 8; ++c)
            wf3[c] = *reinterpret_cast<const bf16x8*>(p3 + (size_t)c * 512);
    }

    float pacc = 0.f;

#pragma unroll 1
    for (int mb = 0; mb < 4; ++mb) {
        const int t0  = mb * 64;
        const int buf = mb & 1;
        u16* ksh = k_sh[buf];

        // ---- stage k (bf16, S-swizzled cols) from prefetched registers
        {
            f32x4 kc[4] = { kn[0], kn[1], kn[2], kn[3] };
            if (mb < 3) load_k4(Kin, b, t0 + 64 + r, c0, kn);
            u32x4 ua = { pkbf(kc[0][0], kc[0][1]), pkbf(kc[0][2], kc[0][3]),
                         pkbf(kc[1][0], kc[1][1]), pkbf(kc[1][2], kc[1][3]) };
            u32x4 ub = { pkbf(kc[2][0], kc[2][1]), pkbf(kc[2][2], kc[2][3]),
                         pkbf(kc[3][0], kc[3][1]), pkbf(kc[3][2], kc[3][3]) };
            *reinterpret_cast<u32x4*>(ksh + r * 72 + (c0 ^ (Sr << 3)))       = ua;
            *reinterpret_cast<u32x4*>(ksh + r * 72 + ((c0 + 8) ^ (Sr << 3))) = ub;
            if (c0 == 0) k0_sh[buf][r] = kc[0][0];
        }
        __syncthreads();                                            // (1) k ready

        // ---- layer1: K=64 folded-M; dual chains (mt=w, w+4) share B-frags
#pragma unroll
        for (int tt = 0; tt < 2; ++tt) {
            const u16* ap0 = A1p + (((size_t)((mb * 2 + tt) * 8 + w) * 64 + lane) << 4);
            const u16* ap1 = A1p + (((size_t)((mb * 2 + tt) * 8 + w + 4) * 64 + lane) << 4);
            u16x8 av00 = *reinterpret_cast<const u16x8*>(ap0);
            u16x8 av01 = *reinterpret_cast<const u16x8*>(ap0 + 8);
            u16x8 av10 = *reinterpret_cast<const u16x8*>(ap1);
            u16x8 av11 = *reinterpret_cast<const u16x8*>(ap1 + 8);
            const u16* xb = ksh + (tt * 32 + tl) * 72 + ((hl ^ S) << 3);
            bf16x8 kf[4];
#pragma unroll
            for (int c = 0; c < 4; ++c)
                kf[c] = *reinterpret_cast<const bf16x8*>(xb + c * 16);
            floatx16 acc0, acc1, zz;
#pragma unroll
            for (int q = 0; q < 4; ++q) {
                f32x4 b0 = *reinterpret_cast<const f32x4*>(&fb1_sh[w * 32 + q * 8 + hsel]);
                f32x4 b1v = *reinterpret_cast<const f32x4*>(&fb1_sh[(w + 4) * 32 + q * 8 + hsel]);
#pragma unroll
                for (int i = 0; i < 4; ++i) {
                    acc0[q * 4 + i] = b0[i]; acc1[q * 4 + i] = b1v[i]; zz[q * 4 + i] = 0.f;
                }
            }
#pragma unroll
            for (int c = 0; c < 4; ++c) {
                acc0 = __builtin_amdgcn_mfma_f32_32x32x16_bf16(mf[0][c], kf[c], acc0, 0, 0, 0);
                acc1 = __builtin_amdgcn_mfma_f32_32x32x16_bf16(mf[1][c], kf[c], acc1, 0, 0, 0);
            }
            u16* yr = h1s + (tt * 32 + tl) * 264;
            store_tile(yr + w * 32 + hsel, S, acc0, zz, av00, av01);
            store_tile(yr + (w + 4) * 32 + hsel, S, acc1, zz, av10, av11);
        }
        __syncthreads();                                            // (2) h1 ready

        // ---- layer2: persistent wf2 (mt=w); 4-ahead preload, dual acc chains
#pragma unroll
        for (int tt = 0; tt < 2; ++tt) {
            const u16* ap = A2p + (((size_t)((mb * 2 + tt) * 4 + w) * 64 + lane) << 4);
            u16x8 av0 = *reinterpret_cast<const u16x8*>(ap);
            u16x8 av1 = *reinterpret_cast<const u16x8*>(ap + 8);
            const u16* xb = h1s + (tt * 32 + tl) * 264 + ((hl ^ S) << 3);
            floatx16 accA, accB;
#pragma unroll
            for (int q = 0; q < 4; ++q) {
                f32x4 bv = *reinterpret_cast<const f32x4*>(&b2_sh[w * 32 + q * 8 + hsel]);
#pragma unroll
                for (int i = 0; i < 4; ++i) { accA[q * 4 + i] = bv[i]; accB[q * 4 + i] = 0.f; }
            }
            bf16x8 cur[4];
#pragma unroll
            for (int c = 0; c < 4; ++c)
                cur[c] = *reinterpret_cast<const bf16x8*>(xb + c * 16);
#pragma unroll
            for (int g = 0; g < 4; ++g) {
                bf16x8 nxt[4];
                if (g < 3) {
#pragma unroll
                    for (int c = 0; c < 4; ++c)
                        nxt[c] = *reinterpret_cast<const bf16x8*>(xb + ((g + 1) * 4 + c) * 16);
                }
                if (g & 1) {
#pragma unroll
                    for (int c = 0; c < 4; ++c)
                        accB = __builtin_amdgcn_mfma_f32_32x32x16_bf16(wf2[g * 4 + c], cur[c], accB, 0, 0, 0);
                } else {
#pragma unroll
                    for (int c = 0; c < 4; ++c)
                        accA = __builtin_amdgcn_mfma_f32_32x32x16_bf16(wf2[g * 4 + c], cur[c], accA, 0, 0, 0);
                }
                if (g < 3) {
#pragma unroll
                    for (int c = 0; c < 4; ++c) cur[c] = nxt[c];
                }
            }
            store_tile(h2s + (tt * 32 + tl) * 136 + w * 32 + hsel, S, accA, accB, av0, av1);
        }
        __syncthreads();                                            // (3) h2 ready

        // ---- layer3 + fused score: acc stays in regs, dot with Wl, no h3 store
        {
            const u16* ap = A3p + (((size_t)((mb * 2 + tt3) * 2 + mt3) * 64 + lane) << 4);
            u16x8 av0 = *reinterpret_cast<const u16x8*>(ap);
            u16x8 av1 = *reinterpret_cast<const u16x8*>(ap + 8);
            f32x4 wlq[4];
#pragma unroll
            for (int q = 0; q < 4; ++q)
                wlq[q] = *reinterpret_cast<const f32x4*>(Wl + mt3 * 32 + q * 8 + hsel);
            const u16* xb = h2s + (tt3 * 32 + tl) * 136 + ((hl ^ S) << 3);
            floatx16 accA, accB;
#pragma unroll
            for (int q = 0; q < 4; ++q) {
                f32x4 bv = *reinterpret_cast<const f32x4*>(&b3_sh[mt3 * 32 + q * 8 + hsel]);
#pragma unroll
                for (int i = 0; i < 4; ++i) { accA[q * 4 + i] = bv[i]; accB[q * 4 + i] = 0.f; }
            }
            bf16x8 cur[4], nxt[4];
#pragma unroll
            for (int c = 0; c < 4; ++c)
                cur[c] = *reinterpret_cast<const bf16x8*>(xb + c * 16);
#pragma unroll
            for (int c = 0; c < 4; ++c)
                nxt[c] = *reinterpret_cast<const bf16x8*>(xb + (4 + c) * 16);
#pragma unroll
            for (int c = 0; c < 4; ++c) {
                accA = __builtin_amdgcn_mfma_f32_32x32x16_bf16(wf3[c], cur[c], accA, 0, 0, 0);
                accB = __builtin_amdgcn_mfma_f32_32x32x16_bf16(wf3[4 + c], nxt[c], accB, 0, 0, 0);
            }
            float s = 0.f;
#pragma unroll
            for (int q = 0; q < 4; ++q) {
#pragma unroll
                for (int i = 0; i < 4; ++i) {
                    const int rr = q * 4 + i;
                    float v = accA[rr] + accB[rr];
                    float al = bf2f(rr < 8 ? av0[rr] : av1[rr - 8]);
                    float p = fmaxf(v, 0.f) + al * fminf(v, 0.f);
                    s += p * wlq[q][i];
                }
            }
            s += __shfl_xor(s, 32);
            if (hl == 0) scorep[mt3][tt3 * 32 + tl] = s;
        }
        __syncthreads();                                            // (4) scores ready

        // ---- pool (k_sh double-buffered: no trailing barrier)
        {
            float sc_l = scorep[0][lane] + scorep[1][lane] + bl0;
            const int t = t0 + lane;
            if (t >= TT || k0_sh[buf][lane] == 0.f) sc_l = 0.f;
#pragma unroll
            for (int i = 0; i < 16; ++i) {
                const int row = w * 16 + i;
                float si = __shfl(sc_l, row);
                pacc += si * bf2f(ksh[row * 72 + (lane ^ (((row >> 3) & 1) << 3))]);
            }
        }
    }

    pool_red[w][lane] = pacc;
    __syncthreads();
    if (tid < 64) {
        Out[(size_t)b * DD + tid] = pool_red[0][tid] + pool_red[1][tid]
                                  + pool_red[2][tid] + pool_red[3][tid];
    }
}

extern "C" void kernel_launch(void* const* d_in, const int* in_sizes, int n_in,
                              void* d_out, int out_size, void* d_ws, size_t ws_size,
                              hipStream_t stream) {
    (void)in_sizes; (void)n_in; (void)out_size; (void)ws_size;
    const float* Q  = (const float*)d_in[0];
    const float* Kk = (const float*)d_in[1];
    const float* W1 = (const float*)d_in[2];
    const float* b1 = (const float*)d_in[3];
    const float* a1 = (const float*)d_in[4];
    const float* W2 = (const float*)d_in[5];
    const float* b2 = (const float*)d_in[6];
    const float* a2 = (const float*)d_in[7];
    const float* W3 = (const float*)d_in[8];
    const float* b3 = (const float*)d_in[9];
    const float* a3 = (const float*)d_in[10];
    const float* Wl = (const float*)d_in[11];
    const float* bl = (const float*)d_in[12];
    float* Out = (float*)d_out;

    u16* ws    = (u16*)d_ws;
    u16* W1kdp = ws;                       // 16384 bf16
    u16* W1pp  = W1kdp + 16384;            // 16384
    u16* W1qdp = W1pp  + 16384;            // 16384
    u16* W2p   = W1qdp + 16384;            // 32768
    u16* W3p   = W2p   + 32768;            //  8192
    u16* A1p   = W3p   + 8192;             // 65536
    u16* A2p   = A1p   + 65536;            // 32768
    u16* A3p   = A2p   + 32768;            // 16384

    hipLaunchKernelGGL(pack_all, dim3(800), dim3(256), 0, stream,
                       W1, W2, W3, a1, a2, a3,
                       W1kdp, W1pp, W1qdp, W2p, W3p, A1p, A2p, A3p);
    hipLaunchKernelGGL(attn_pool_kernel, dim3(BB), dim3(256), 0, stream,
                       Q, Kk, W1kdp, W1pp, W1qdp, b1, A1p, W2p, b2, A2p,
                       W3p, b3, A3p, Wl, bl, Out);
}